// Round 4
// baseline (224.441 us; speedup 1.0000x reference)
//
#include <hip/hip_runtime.h>

// Problem constants
#define BATCH 8
#define HH 56
#define WW 56
#define NPOS (BATCH*HH*WW)   // 25088
#define C 256
#define P 32
#define D 4
#define J 128
#define EPS 1e-3f

typedef __attribute__((ext_vector_type(8))) short bf16x8_t;
typedef __attribute__((ext_vector_type(4))) float f32x4_t;

__device__ __forceinline__ unsigned short f2bf(float f) {
    union { float f; unsigned int i; } v; v.f = f;
    unsigned int r = v.i + 0x7fffu + ((v.i >> 16) & 1u);   // RNE
    return (unsigned short)(r >> 16);
}
// pack float4 -> 4 bf16 (truncation; verified adequate in round 3)
__device__ __forceinline__ uint2 pack4_trunc(float4 v) {
    uint2 r;
    r.x = __builtin_amdgcn_perm(__float_as_uint(v.y), __float_as_uint(v.x), 0x07060302u);
    r.y = __builtin_amdgcn_perm(__float_as_uint(v.w), __float_as_uint(v.z), 0x07060302u);
    return r;
}

// ---------------------------------------------------------------------------
// Fold BN into conv weights/biases. Outputs:
//   W1bf: bf16 [j=128][c=256]       (stage1 A-operand, row-major j,c)
//   b1f : fp32 [128]
//   w2q : fp32 [(k9*4+di)*128 + p*4 + do]   (p-major float4 per (k9,di,p))
//   b2t : fp32 [do*32 + p]
//   WB  : bf16 [p][c][8] = {w0,w1,w2,w3,bias,0,0,0}   (stage3 B-frag + k=4 bias)
// ---------------------------------------------------------------------------
__global__ __launch_bounds__(256) void fold_params(
    const float* __restrict__ W1, const float* __restrict__ B1,
    const float* __restrict__ W2, const float* __restrict__ B2,
    const float* __restrict__ W3, const float* __restrict__ B3,
    const float* __restrict__ G1, const float* __restrict__ Be1,
    const float* __restrict__ M1, const float* __restrict__ V1,
    const float* __restrict__ G2, const float* __restrict__ Be2,
    const float* __restrict__ M2, const float* __restrict__ V2,
    const float* __restrict__ G3, const float* __restrict__ Be3,
    const float* __restrict__ M3, const float* __restrict__ V3,
    unsigned short* __restrict__ W1bf, float* __restrict__ b1f,
    float* __restrict__ w2q, float* __restrict__ b2t,
    unsigned short* __restrict__ WB)
{
    int idx = blockIdx.x * 256 + threadIdx.x;

    if (idx < C*J) {                       // W1bf[j][c]
        int j = idx >> 8, c = idx & 255;
        int p = j >> 2, d = j & 3;
        float s = G1[j] * rsqrtf(V1[j] + EPS);
        W1bf[idx] = f2bf(W1[(p*C + c)*D + d] * s);
        return;
    }
    idx -= C*J;
    if (idx < J) {
        float s = G1[idx] * rsqrtf(V1[idx] + EPS);
        b1f[idx] = B1[idx] * s + Be1[idx] - M1[idx] * s;
        return;
    }
    idx -= J;
    if (idx < 9*D*D*P) {                   // w2q
        int do_ = idx & 3, p = (idx >> 2) & 31;
        int r2 = idx >> 7, di = r2 & 3, k9 = r2 >> 2;
        int j = p*4 + do_;
        float s = G2[j] * rsqrtf(V2[j] + EPS);
        w2q[idx] = W2[((p*9 + k9)*4 + di)*4 + do_] * s;
        return;
    }
    idx -= 9*D*D*P;
    if (idx < J) {                         // b2t[do][p]
        int do_ = idx >> 5, p = idx & 31;
        int j = p*4 + do_;
        float s = G2[j] * rsqrtf(V2[j] + EPS);
        b2t[idx] = B2[j] * s + Be2[j] - M2[j] * s;
        return;
    }
    idx -= J;
    if (idx < P*C*8) {                     // WB[p][c][s]
        int s8 = idx & 7;
        int c = (idx >> 3) & 255;
        int p = idx >> 11;
        float sc = G3[p*C + c] * rsqrtf(V3[p*C + c] + EPS);
        float v = 0.f;
        if (s8 < 4)       v = W3[(p*D + s8)*C + c] * sc;
        else if (s8 == 4) v = B3[p*C + c] * sc + Be3[p*C + c] - M3[p*C + c] * sc;
        WB[idx] = f2bf(v);
        return;
    }
}

// ---------------------------------------------------------------------------
// Stage 1 (MFMA): h1[n][j] = relu( sum_c W1bf[j][c]*x[n][c] + b1f[j] ), bf16 out.
// D[j][n] = A(W)·B(x). Block: 4 waves, wave = j-range 32 (A-frags in regs),
// block n-tile = 32 staged once in XOR-swizzled LDS (full K resident).
// ---------------------------------------------------------------------------
__global__ __launch_bounds__(256) void stage1(
    const float* __restrict__ x, const unsigned short* __restrict__ W1bf,
    const float* __restrict__ b1f, unsigned short* __restrict__ h1)
{
    __shared__ unsigned short xs[32*256];   // row n, 32 groups of 8; group g stored at g^(n&7)

    const int tid = threadIdx.x;
    const int n0 = blockIdx.x * 32;
    const int wid = tid >> 6, l = tid & 63, l15 = l & 15, quad = l >> 4;
    const int j0w = wid * 32;

    // A-frags (W): 2 j-frags x 8 k-chunks, registers
    union bu { uint4 u; bf16x8_t v; };
    bu aw[2][8];
#pragma unroll
    for (int jf = 0; jf < 2; ++jf) {
        int row = j0w + jf*16 + l15;
#pragma unroll
        for (int kc = 0; kc < 8; ++kc)
            aw[jf][kc].u = *(const uint4*)&W1bf[row*C + kc*32 + quad*8];
    }

    // stage x tile: 32 rows x 256 cols, fp32 -> bf16, XOR-swizzled
#pragma unroll
    for (int it = 0; it < 4; ++it) {
        int row = tid >> 3;
        int g = (tid & 7) + it*8;
        const float* xp = &x[(size_t)(n0 + row) * C + g*8];
        float4 v0 = *(const float4*)xp;
        float4 v1 = *(const float4*)(xp + 4);
        uint2 p0 = pack4_trunc(v0), p1 = pack4_trunc(v1);
        uint4 st; st.x = p0.x; st.y = p0.y; st.z = p1.x; st.w = p1.y;
        *(uint4*)&xs[row*256 + ((g ^ (row & 7)) * 8)] = st;
    }
    __syncthreads();

    f32x4_t acc[2][2];
#pragma unroll
    for (int jf = 0; jf < 2; ++jf)
#pragma unroll
        for (int nf = 0; nf < 2; ++nf) acc[jf][nf] = (f32x4_t){0.f,0.f,0.f,0.f};

#pragma unroll
    for (int kc = 0; kc < 8; ++kc) {
#pragma unroll
        for (int nf = 0; nf < 2; ++nf) {
            int row = nf*16 + l15;
            int g = (kc*4 + quad) ^ (row & 7);
            bf16x8_t b = *(const bf16x8_t*)&xs[row*256 + g*8];
            acc[0][nf] = __builtin_amdgcn_mfma_f32_16x16x32_bf16(aw[0][kc].v, b, acc[0][nf], 0, 0, 0);
            acc[1][nf] = __builtin_amdgcn_mfma_f32_16x16x32_bf16(aw[1][kc].v, b, acc[1][nf], 0, 0, 0);
        }
    }

    // epilogue: D row = j = j0w + jf*16 + quad*4 + r ; col = n = n0 + nf*16 + l15
#pragma unroll
    for (int jf = 0; jf < 2; ++jf) {
        int jb = j0w + jf*16 + quad*4;
        float4 bias = *(const float4*)&b1f[jb];
#pragma unroll
        for (int nf = 0; nf < 2; ++nf) {
            int n = n0 + nf*16 + l15;
            float v0 = fmaxf(acc[jf][nf][0] + bias.x, 0.f);
            float v1 = fmaxf(acc[jf][nf][1] + bias.y, 0.f);
            float v2 = fmaxf(acc[jf][nf][2] + bias.z, 0.f);
            float v3 = fmaxf(acc[jf][nf][3] + bias.w, 0.f);
            uint2 o;
            o.x = (unsigned int)f2bf(v0) | ((unsigned int)f2bf(v1) << 16);
            o.y = (unsigned int)f2bf(v2) | ((unsigned int)f2bf(v3) << 16);
            *(uint2*)&h1[(size_t)n * J + jb] = o;
        }
    }
}

// ---------------------------------------------------------------------------
// Stage 2: grouped 3x3 conv (32 groups of 4->4), SAME, +bias, ReLU. bf16 in/out.
// One thread per (n,p). Weights in LDS p-major: lane-p reads are conflict-free
// float4 per (k9, di).
// ---------------------------------------------------------------------------
__global__ __launch_bounds__(256) void stage2(
    const unsigned short* __restrict__ h1,
    const float* __restrict__ w2q, const float* __restrict__ b2t,
    unsigned short* __restrict__ h2)
{
    __shared__ float ws[9*16*32];    // 4608 floats, [(k9*4+di)*128 + p*4 + do]
    __shared__ float bs[128];        // [do*32 + p]

    const int tid = threadIdx.x;
    for (int i = tid; i < 4608; i += 256) ws[i] = w2q[i];
    if (tid < 128) bs[tid] = b2t[tid];
    __syncthreads();

    const int t = blockIdx.x * 256 + tid;
    const int p = t & 31;
    const int n = t >> 5;
    const int w = n % WW;
    const int h = (n / WW) % HH;
    const int b = n / (HH*WW);

    float a0 = bs[p], a1 = bs[32 + p], a2 = bs[64 + p], a3 = bs[96 + p];

#pragma unroll
    for (int ky = 0; ky < 3; ++ky) {
        int yy = h + ky - 1;
        if (yy < 0 || yy >= HH) continue;
#pragma unroll
        for (int kx = 0; kx < 3; ++kx) {
            int xx = w + kx - 1;
            if (xx < 0 || xx >= WW) continue;
            uint2 hv = *(const uint2*)&h1[(size_t)((b*HH + yy)*WW + xx) * J + p*4];
            float f0 = __uint_as_float(hv.x << 16);
            float f1 = __uint_as_float(hv.x & 0xffff0000u);
            float f2 = __uint_as_float(hv.y << 16);
            float f3 = __uint_as_float(hv.y & 0xffff0000u);
            const float* wp = &ws[(ky*3 + kx) * 512 + p*4];
            float4 w0 = *(const float4*)&wp[0];     // di=0
            float4 w1 = *(const float4*)&wp[128];   // di=1
            float4 w2v = *(const float4*)&wp[256];  // di=2
            float4 w3v = *(const float4*)&wp[384];  // di=3
            a0 = fmaf(f0, w0.x, a0);  a1 = fmaf(f0, w0.y, a1);
            a2 = fmaf(f0, w0.z, a2);  a3 = fmaf(f0, w0.w, a3);
            a0 = fmaf(f1, w1.x, a0);  a1 = fmaf(f1, w1.y, a1);
            a2 = fmaf(f1, w1.z, a2);  a3 = fmaf(f1, w1.w, a3);
            a0 = fmaf(f2, w2v.x, a0); a1 = fmaf(f2, w2v.y, a1);
            a2 = fmaf(f2, w2v.z, a2); a3 = fmaf(f2, w2v.w, a3);
            a0 = fmaf(f3, w3v.x, a0); a1 = fmaf(f3, w3v.y, a1);
            a2 = fmaf(f3, w3v.z, a2); a3 = fmaf(f3, w3v.w, a3);
        }
    }
    uint2 o;
    o.x = (unsigned int)f2bf(fmaxf(a0, 0.f)) | ((unsigned int)f2bf(fmaxf(a1, 0.f)) << 16);
    o.y = (unsigned int)f2bf(fmaxf(a2, 0.f)) | ((unsigned int)f2bf(fmaxf(a3, 0.f)) << 16);
    *(uint2*)&h2[(size_t)n * J + p*4] = o;
}

// ---------------------------------------------------------------------------
// Stage 3 (MFMA): out[n][c] = relu( x[n][c] + sum_p relu( h2_p . W3_p + b3_p ) )
// Wave owns one 16-wide c group; 32 B-frags (weights+bias@k4) live in VGPRs.
// A-frag: h2 row (k0..3) + constant 1.0 at k4. cin = persistent zero tuple.
// Block: 4 waves (c-range 64), n-tile 128 (8 passes). Grid 196 x 4 = 784.
// ---------------------------------------------------------------------------
__global__ __launch_bounds__(256) void stage3(
    const unsigned short* __restrict__ h2,
    const unsigned short* __restrict__ WB,
    const float* __restrict__ x, float* __restrict__ out)
{
    const int tid = threadIdx.x;
    const int bx = blockIdx.x;
    const int cchunk = bx & 3, nchunk = bx >> 2;
    const int wid = tid >> 6, l = tid & 63, l15 = l & 15, quad = l >> 4;
    const int c = cchunk*64 + wid*16 + l15;
    const int n0 = nchunk * 128;

    union bu { uint4 u; bf16x8_t v; };
    bu bw[32];
#pragma unroll
    for (int p = 0; p < 32; ++p) { bw[p].u.x = 0u; bw[p].u.y = 0u; bw[p].u.z = 0u; bw[p].u.w = 0u; }
    if (quad == 0) {
#pragma unroll
        for (int p = 0; p < 32; ++p)
            bw[p].u = *(const uint4*)&WB[((size_t)p*C + c)*8];
    }

    const uint2 acons = make_uint2(0x3f80u, 0u);   // A[k4]=1.0 bf16, rest 0
    const f32x4_t zero = (f32x4_t){0.f, 0.f, 0.f, 0.f};

    for (int pass = 0; pass < 8; ++pass) {
        const int nb = n0 + pass*16;
        f32x4_t acc = zero;
#pragma unroll
        for (int p = 0; p < 32; ++p) {
            union { uint2 u[2]; bf16x8_t v; } af;
            af.u[0] = *(const uint2*)&h2[(size_t)(nb + l15) * J + p*4];
            af.u[1] = acons;
            f32x4_t z = __builtin_amdgcn_mfma_f32_16x16x32_bf16(af.v, bw[p].v, zero, 0, 0, 0);
            acc[0] += fmaxf(z[0], 0.f);
            acc[1] += fmaxf(z[1], 0.f);
            acc[2] += fmaxf(z[2], 0.f);
            acc[3] += fmaxf(z[3], 0.f);
        }
#pragma unroll
        for (int r = 0; r < 4; ++r) {
            int n = nb + quad*4 + r;
            float v = acc[r] + x[(size_t)n * C + c];
            out[(size_t)n * C + c] = fmaxf(v, 0.f);
        }
    }
}

// ---------------------------------------------------------------------------
extern "C" void kernel_launch(void* const* d_in, const int* in_sizes, int n_in,
                              void* d_out, int out_size, void* d_ws, size_t ws_size,
                              hipStream_t stream) {
    const float* x  = (const float*)d_in[0];
    const float* W1 = (const float*)d_in[1];
    const float* B1 = (const float*)d_in[2];
    const float* W2 = (const float*)d_in[3];
    const float* B2 = (const float*)d_in[4];
    const float* W3 = (const float*)d_in[5];
    const float* B3 = (const float*)d_in[6];
    const float* G1 = (const float*)d_in[7];
    const float* Be1= (const float*)d_in[8];
    const float* M1 = (const float*)d_in[9];
    const float* V1 = (const float*)d_in[10];
    const float* G2 = (const float*)d_in[11];
    const float* Be2= (const float*)d_in[12];
    const float* M2 = (const float*)d_in[13];
    const float* V2 = (const float*)d_in[14];
    const float* G3 = (const float*)d_in[15];
    const float* Be3= (const float*)d_in[16];
    const float* M3 = (const float*)d_in[17];
    const float* V3 = (const float*)d_in[18];

    char* wsb = (char*)d_ws;
    unsigned short* h1   = (unsigned short*)(wsb + 0);          // 6,422,528 B
    unsigned short* h2   = (unsigned short*)(wsb + 6422528);    // 6,422,528 B
    unsigned short* W1bf = (unsigned short*)(wsb + 12845056);   // 65,536 B
    unsigned short* WB   = (unsigned short*)(wsb + 12910592);   // 131,072 B
    float*          w2q  = (float*)(wsb + 13041664);            // 18,432 B
    float*          b1f  = (float*)(wsb + 13060096);            // 512 B
    float*          b2t  = (float*)(wsb + 13060608);            // 512 B

    const int fold_tasks = C*J + J + 9*D*D*P + J + P*C*8;       // 103,168
    fold_params<<<(fold_tasks + 255)/256, 256, 0, stream>>>(
        W1, B1, W2, B2, W3, B3, G1, Be1, M1, V1, G2, Be2, M2, V2,
        G3, Be3, M3, V3, W1bf, b1f, w2q, b2t, WB);

    stage1<<<NPOS/32, 256, 0, stream>>>(x, W1bf, b1f, h1);
    stage2<<<(NPOS*P)/256, 256, 0, stream>>>(h1, w2q, b2t, h2);
    stage3<<<(NPOS/128)*4, 256, 0, stream>>>(h2, WB, x, (float*)d_out);
}

// Round 6
// 179.526 us; speedup vs baseline: 1.2502x; 1.2502x over previous
//
#include <hip/hip_runtime.h>

// Problem constants
#define BATCH 8
#define HH 56
#define WW 56
#define NPOS (BATCH*HH*WW)   // 25088
#define C 256
#define P 32
#define D 4
#define J 128
#define EPS 1e-3f

typedef __attribute__((ext_vector_type(8))) short bf16x8_t;
typedef __attribute__((ext_vector_type(4))) float f32x4_t;

__device__ __forceinline__ unsigned short f2bf(float f) {
    union { float f; unsigned int i; } v; v.f = f;
    unsigned int r = v.i + 0x7fffu + ((v.i >> 16) & 1u);   // RNE
    return (unsigned short)(r >> 16);
}
// pack float4 -> 4 bf16 (truncation; verified adequate in round 3)
__device__ __forceinline__ uint2 pack4_trunc(float4 v) {
    uint2 r;
    r.x = __builtin_amdgcn_perm(__float_as_uint(v.y), __float_as_uint(v.x), 0x07060302u);
    r.y = __builtin_amdgcn_perm(__float_as_uint(v.w), __float_as_uint(v.z), 0x07060302u);
    return r;
}

// ---------------------------------------------------------------------------
// Fold BN into conv weights/biases. Outputs:
//   W1bf: bf16 [j=128][c=256]       (stage1 A-operand, row-major j,c)
//   b1f : fp32 [128]
//   w2q : fp32 [(k9*4+di)*128 + p*4 + do]   (p-major float4 per (k9,di,p))
//   b2t : fp32 [do*32 + p]
//   WB  : bf16 [p][c][8] = {w0,w1,w2,w3,bias,0,0,0}   (stage3 B-frag + k=4 bias)
// ---------------------------------------------------------------------------
__global__ __launch_bounds__(256) void fold_params(
    const float* __restrict__ W1, const float* __restrict__ B1,
    const float* __restrict__ W2, const float* __restrict__ B2,
    const float* __restrict__ W3, const float* __restrict__ B3,
    const float* __restrict__ G1, const float* __restrict__ Be1,
    const float* __restrict__ M1, const float* __restrict__ V1,
    const float* __restrict__ G2, const float* __restrict__ Be2,
    const float* __restrict__ M2, const float* __restrict__ V2,
    const float* __restrict__ G3, const float* __restrict__ Be3,
    const float* __restrict__ M3, const float* __restrict__ V3,
    unsigned short* __restrict__ W1bf, float* __restrict__ b1f,
    float* __restrict__ w2q, float* __restrict__ b2t,
    unsigned short* __restrict__ WB)
{
    int idx = blockIdx.x * 256 + threadIdx.x;

    if (idx < C*J) {                       // W1bf[j][c]
        int j = idx >> 8, c = idx & 255;
        int p = j >> 2, d = j & 3;
        float s = G1[j] * rsqrtf(V1[j] + EPS);
        W1bf[idx] = f2bf(W1[(p*C + c)*D + d] * s);
        return;
    }
    idx -= C*J;
    if (idx < J) {
        float s = G1[idx] * rsqrtf(V1[idx] + EPS);
        b1f[idx] = B1[idx] * s + Be1[idx] - M1[idx] * s;
        return;
    }
    idx -= J;
    if (idx < 9*D*D*P) {                   // w2q
        int do_ = idx & 3, p = (idx >> 2) & 31;
        int r2 = idx >> 7, di = r2 & 3, k9 = r2 >> 2;
        int j = p*4 + do_;
        float s = G2[j] * rsqrtf(V2[j] + EPS);
        w2q[idx] = W2[((p*9 + k9)*4 + di)*4 + do_] * s;
        return;
    }
    idx -= 9*D*D*P;
    if (idx < J) {                         // b2t[do][p]
        int do_ = idx >> 5, p = idx & 31;
        int j = p*4 + do_;
        float s = G2[j] * rsqrtf(V2[j] + EPS);
        b2t[idx] = B2[j] * s + Be2[j] - M2[j] * s;
        return;
    }
    idx -= J;
    if (idx < P*C*8) {                     // WB[p][c][s]
        int s8 = idx & 7;
        int c = (idx >> 3) & 255;
        int p = idx >> 11;
        float sc = G3[p*C + c] * rsqrtf(V3[p*C + c] + EPS);
        float v = 0.f;
        if (s8 < 4)       v = W3[(p*D + s8)*C + c] * sc;
        else if (s8 == 4) v = B3[p*C + c] * sc + Be3[p*C + c] - M3[p*C + c] * sc;
        WB[idx] = f2bf(v);
        return;
    }
}

// ---------------------------------------------------------------------------
// Stage 1 (MFMA): h1[n][j] = relu( sum_c W1bf[j][c]*x[n][c] + b1f[j] ), bf16 out.
// D[j][n] = A(W)·B(x). Block: 4 waves, wave = j-range 32 (A-frags in regs),
// block n-tile = 32 staged once in XOR-swizzled LDS (full K resident).
// ---------------------------------------------------------------------------
__global__ __launch_bounds__(256) void stage1(
    const float* __restrict__ x, const unsigned short* __restrict__ W1bf,
    const float* __restrict__ b1f, unsigned short* __restrict__ h1)
{
    __shared__ unsigned short xs[32*256];   // row n, 32 groups of 8; group g stored at g^(n&7)

    const int tid = threadIdx.x;
    const int n0 = blockIdx.x * 32;
    const int wid = tid >> 6, l = tid & 63, l15 = l & 15, quad = l >> 4;
    const int j0w = wid * 32;

    // A-frags (W): 2 j-frags x 8 k-chunks, registers
    union bu { uint4 u; bf16x8_t v; };
    bu aw[2][8];
#pragma unroll
    for (int jf = 0; jf < 2; ++jf) {
        int row = j0w + jf*16 + l15;
#pragma unroll
        for (int kc = 0; kc < 8; ++kc)
            aw[jf][kc].u = *(const uint4*)&W1bf[row*C + kc*32 + quad*8];
    }

    // stage x tile: 32 rows x 256 cols, fp32 -> bf16, XOR-swizzled
#pragma unroll
    for (int it = 0; it < 4; ++it) {
        int row = tid >> 3;
        int g = (tid & 7) + it*8;
        const float* xp = &x[(size_t)(n0 + row) * C + g*8];
        float4 v0 = *(const float4*)xp;
        float4 v1 = *(const float4*)(xp + 4);
        uint2 p0 = pack4_trunc(v0), p1 = pack4_trunc(v1);
        uint4 st; st.x = p0.x; st.y = p0.y; st.z = p1.x; st.w = p1.y;
        *(uint4*)&xs[row*256 + ((g ^ (row & 7)) * 8)] = st;
    }
    __syncthreads();

    f32x4_t acc[2][2];
#pragma unroll
    for (int jf = 0; jf < 2; ++jf)
#pragma unroll
        for (int nf = 0; nf < 2; ++nf) acc[jf][nf] = (f32x4_t){0.f,0.f,0.f,0.f};

#pragma unroll
    for (int kc = 0; kc < 8; ++kc) {
#pragma unroll
        for (int nf = 0; nf < 2; ++nf) {
            int row = nf*16 + l15;
            int g = (kc*4 + quad) ^ (row & 7);
            bf16x8_t b = *(const bf16x8_t*)&xs[row*256 + g*8];
            acc[0][nf] = __builtin_amdgcn_mfma_f32_16x16x32_bf16(aw[0][kc].v, b, acc[0][nf], 0, 0, 0);
            acc[1][nf] = __builtin_amdgcn_mfma_f32_16x16x32_bf16(aw[1][kc].v, b, acc[1][nf], 0, 0, 0);
        }
    }

    // epilogue: D row = j = j0w + jf*16 + quad*4 + r ; col = n = n0 + nf*16 + l15
#pragma unroll
    for (int jf = 0; jf < 2; ++jf) {
        int jb = j0w + jf*16 + quad*4;
        float4 bias = *(const float4*)&b1f[jb];
#pragma unroll
        for (int nf = 0; nf < 2; ++nf) {
            int n = n0 + nf*16 + l15;
            float v0 = fmaxf(acc[jf][nf][0] + bias.x, 0.f);
            float v1 = fmaxf(acc[jf][nf][1] + bias.y, 0.f);
            float v2 = fmaxf(acc[jf][nf][2] + bias.z, 0.f);
            float v3 = fmaxf(acc[jf][nf][3] + bias.w, 0.f);
            uint2 o;
            o.x = (unsigned int)f2bf(v0) | ((unsigned int)f2bf(v1) << 16);
            o.y = (unsigned int)f2bf(v2) | ((unsigned int)f2bf(v3) << 16);
            *(uint2*)&h1[(size_t)n * J + jb] = o;
        }
    }
}

// ---------------------------------------------------------------------------
// Stage 2: grouped 3x3 conv (32 groups of 4->4), SAME, +bias, ReLU. bf16 in/out.
// One thread per (n,p). Weights in LDS p-major: lane-p reads are conflict-free
// float4 per (k9, di).
// ---------------------------------------------------------------------------
__global__ __launch_bounds__(256) void stage2(
    const unsigned short* __restrict__ h1,
    const float* __restrict__ w2q, const float* __restrict__ b2t,
    unsigned short* __restrict__ h2)
{
    __shared__ float ws[9*16*32];    // 4608 floats, [(k9*4+di)*128 + p*4 + do]
    __shared__ float bs[128];        // [do*32 + p]

    const int tid = threadIdx.x;
    for (int i = tid; i < 4608; i += 256) ws[i] = w2q[i];
    if (tid < 128) bs[tid] = b2t[tid];
    __syncthreads();

    const int t = blockIdx.x * 256 + tid;
    const int p = t & 31;
    const int n = t >> 5;
    const int w = n % WW;
    const int h = (n / WW) % HH;
    const int b = n / (HH*WW);

    float a0 = bs[p], a1 = bs[32 + p], a2 = bs[64 + p], a3 = bs[96 + p];

#pragma unroll
    for (int ky = 0; ky < 3; ++ky) {
        int yy = h + ky - 1;
        if (yy < 0 || yy >= HH) continue;
#pragma unroll
        for (int kx = 0; kx < 3; ++kx) {
            int xx = w + kx - 1;
            if (xx < 0 || xx >= WW) continue;
            uint2 hv = *(const uint2*)&h1[(size_t)((b*HH + yy)*WW + xx) * J + p*4];
            float f0 = __uint_as_float(hv.x << 16);
            float f1 = __uint_as_float(hv.x & 0xffff0000u);
            float f2 = __uint_as_float(hv.y << 16);
            float f3 = __uint_as_float(hv.y & 0xffff0000u);
            const float* wp = &ws[(ky*3 + kx) * 512 + p*4];
            float4 w0 = *(const float4*)&wp[0];     // di=0
            float4 w1 = *(const float4*)&wp[128];   // di=1
            float4 w2v = *(const float4*)&wp[256];  // di=2
            float4 w3v = *(const float4*)&wp[384];  // di=3
            a0 = fmaf(f0, w0.x, a0);  a1 = fmaf(f0, w0.y, a1);
            a2 = fmaf(f0, w0.z, a2);  a3 = fmaf(f0, w0.w, a3);
            a0 = fmaf(f1, w1.x, a0);  a1 = fmaf(f1, w1.y, a1);
            a2 = fmaf(f1, w1.z, a2);  a3 = fmaf(f1, w1.w, a3);
            a0 = fmaf(f2, w2v.x, a0); a1 = fmaf(f2, w2v.y, a1);
            a2 = fmaf(f2, w2v.z, a2); a3 = fmaf(f2, w2v.w, a3);
            a0 = fmaf(f3, w3v.x, a0); a1 = fmaf(f3, w3v.y, a1);
            a2 = fmaf(f3, w3v.z, a2); a3 = fmaf(f3, w3v.w, a3);
        }
    }
    uint2 o;
    o.x = (unsigned int)f2bf(fmaxf(a0, 0.f)) | ((unsigned int)f2bf(fmaxf(a1, 0.f)) << 16);
    o.y = (unsigned int)f2bf(fmaxf(a2, 0.f)) | ((unsigned int)f2bf(fmaxf(a3, 0.f)) << 16);
    *(uint2*)&h2[(size_t)n * J + p*4] = o;
}

// ---------------------------------------------------------------------------
// Stage 3 (MFMA): out[n][c] = relu( x[n][c] + sum_p relu( h2_p . W3_p + b3_p ) )
// B-frags (weights+bias@k4) register-stationary per wave (quad 0 only, loaded
// ONCE); A-frags from LDS-staged h2 tile (coalesced global load; padded rows
// -> conflict-free quad-broadcast ds_read_b64).
// Block: 4 waves x 16-c; grid = (NPOS/64 n-tiles) x 4 c-chunks.
// ---------------------------------------------------------------------------
#define S3_ROWSTRIDE 132   // shorts; read bank = (66*row + 2p) % 32 -> all 16 rows distinct
__global__ __launch_bounds__(256) void stage3(
    const unsigned short* __restrict__ h2,
    const unsigned short* __restrict__ WB,
    const float* __restrict__ x, float* __restrict__ out)
{
    __shared__ unsigned short h2s[64 * S3_ROWSTRIDE];   // 16,896 B

    const int tid = threadIdx.x;
    const int bx = blockIdx.x;
    const int cchunk = bx & 3, nchunk = bx >> 2;
    const int wid = tid >> 6, l = tid & 63, l15 = l & 15, quad = l >> 4;
    const int c = cchunk*64 + wid*16 + l15;
    const int n0 = nchunk * 64;

    // B-frags: weights + bias(k=4), loaded once, quad 0 only
    union bu { uint4 u; bf16x8_t v; };
    bu bw[32];
#pragma unroll
    for (int p = 0; p < 32; ++p) { bw[p].u.x = 0u; bw[p].u.y = 0u; bw[p].u.z = 0u; bw[p].u.w = 0u; }
    if (quad == 0) {
#pragma unroll
        for (int p = 0; p < 32; ++p)
            bw[p].u = *(const uint4*)&WB[((size_t)p*C + c)*8];
    }

    // stage h2 tile: 64 rows x 128 cols bf16 = 1024 uint4 (FULL tile; r5 bug
    // staged only half). 16 uint4 per row.
#pragma unroll
    for (int it = 0; it < 4; ++it) {
        int idx = it*256 + tid;              // 1024 uint4 total
        int row = idx >> 4, col = (idx & 15) * 8;
        uint4 v = *(const uint4*)&h2[(size_t)(n0 + row) * J + col];
        *(uint4*)&h2s[row * S3_ROWSTRIDE + col] = v;
    }
    __syncthreads();

    const uint2 acons = make_uint2(0x3f80u, 0u);   // A[k4]=1.0 bf16, rest 0
    const f32x4_t zero = (f32x4_t){0.f, 0.f, 0.f, 0.f};

#pragma unroll
    for (int pass = 0; pass < 4; ++pass) {
        const int nb = n0 + pass*16;
        const unsigned short* arow = &h2s[(pass*16 + l15) * S3_ROWSTRIDE];
        f32x4_t acc = zero;
#pragma unroll
        for (int p = 0; p < 32; ++p) {
            union { uint2 u[2]; bf16x8_t v; } af;
            af.u[0] = *(const uint2*)&arow[p*4];   // quad-broadcast, conflict-free
            af.u[1] = acons;
            f32x4_t z = __builtin_amdgcn_mfma_f32_16x16x32_bf16(af.v, bw[p].v, zero, 0, 0, 0);
            acc[0] += fmaxf(z[0], 0.f);
            acc[1] += fmaxf(z[1], 0.f);
            acc[2] += fmaxf(z[2], 0.f);
            acc[3] += fmaxf(z[3], 0.f);
        }
#pragma unroll
        for (int r = 0; r < 4; ++r) {
            int n = nb + quad*4 + r;
            float v = acc[r] + x[(size_t)n * C + c];
            out[(size_t)n * C + c] = fmaxf(v, 0.f);
        }
    }
}

// ---------------------------------------------------------------------------
extern "C" void kernel_launch(void* const* d_in, const int* in_sizes, int n_in,
                              void* d_out, int out_size, void* d_ws, size_t ws_size,
                              hipStream_t stream) {
    const float* x  = (const float*)d_in[0];
    const float* W1 = (const float*)d_in[1];
    const float* B1 = (const float*)d_in[2];
    const float* W2 = (const float*)d_in[3];
    const float* B2 = (const float*)d_in[4];
    const float* W3 = (const float*)d_in[5];
    const float* B3 = (const float*)d_in[6];
    const float* G1 = (const float*)d_in[7];
    const float* Be1= (const float*)d_in[8];
    const float* M1 = (const float*)d_in[9];
    const float* V1 = (const float*)d_in[10];
    const float* G2 = (const float*)d_in[11];
    const float* Be2= (const float*)d_in[12];
    const float* M2 = (const float*)d_in[13];
    const float* V2 = (const float*)d_in[14];
    const float* G3 = (const float*)d_in[15];
    const float* Be3= (const float*)d_in[16];
    const float* M3 = (const float*)d_in[17];
    const float* V3 = (const float*)d_in[18];

    char* wsb = (char*)d_ws;
    unsigned short* h1   = (unsigned short*)(wsb + 0);          // 6,422,528 B
    unsigned short* h2   = (unsigned short*)(wsb + 6422528);    // 6,422,528 B
    unsigned short* W1bf = (unsigned short*)(wsb + 12845056);   // 65,536 B
    unsigned short* WB   = (unsigned short*)(wsb + 12910592);   // 131,072 B
    float*          w2q  = (float*)(wsb + 13041664);            // 18,432 B
    float*          b1f  = (float*)(wsb + 13060096);            // 512 B
    float*          b2t  = (float*)(wsb + 13060608);            // 512 B

    const int fold_tasks = C*J + J + 9*D*D*P + J + P*C*8;       // 103,168
    fold_params<<<(fold_tasks + 255)/256, 256, 0, stream>>>(
        W1, B1, W2, B2, W3, B3, G1, Be1, M1, V1, G2, Be2, M2, V2,
        G3, Be3, M3, V3, W1bf, b1f, w2q, b2t, WB);

    stage1<<<NPOS/32, 256, 0, stream>>>(x, W1bf, b1f, h1);
    stage2<<<(NPOS*P)/256, 256, 0, stream>>>(h1, w2q, b2t, h2);
    stage3<<<(NPOS/64)*4, 256, 0, stream>>>(h2, WB, x, (float*)d_out);
}

// Round 7
// 163.983 us; speedup vs baseline: 1.3687x; 1.0948x over previous
//
#include <hip/hip_runtime.h>

// Problem constants
#define BATCH 8
#define HH 56
#define WW 56
#define NPOS (BATCH*HH*WW)   // 25088
#define C 256
#define P 32
#define D 4
#define J 128
#define EPS 1e-3f

typedef __attribute__((ext_vector_type(8))) short bf16x8_t;
typedef __attribute__((ext_vector_type(4))) float f32x4_t;

__device__ __forceinline__ unsigned short f2bf(float f) {
    union { float f; unsigned int i; } v; v.f = f;
    unsigned int r = v.i + 0x7fffu + ((v.i >> 16) & 1u);   // RNE
    return (unsigned short)(r >> 16);
}
// pack float4 -> 4 bf16 (truncation; verified adequate in round 3)
__device__ __forceinline__ uint2 pack4_trunc(float4 v) {
    uint2 r;
    r.x = __builtin_amdgcn_perm(__float_as_uint(v.y), __float_as_uint(v.x), 0x07060302u);
    r.y = __builtin_amdgcn_perm(__float_as_uint(v.w), __float_as_uint(v.z), 0x07060302u);
    return r;
}

// ---------------------------------------------------------------------------
// Fold BN into conv weights/biases. Outputs:
//   W1bf: bf16 [j=128][c=256]       (stage1 A-operand, row-major j,c)
//   b1f : fp32 [128]
//   w2q : fp32 [(k9*4+di)*128 + p*4 + do]   (p-major float4 per (k9,di,p))
//   b2t : fp32 [do*32 + p]
//   WB  : bf16 [p][c][8] = {w0,w1,w2,w3,bias,0,0,0}   (stage3 B-frag + k=4 bias)
// ---------------------------------------------------------------------------
__global__ __launch_bounds__(256) void fold_params(
    const float* __restrict__ W1, const float* __restrict__ B1,
    const float* __restrict__ W2, const float* __restrict__ B2,
    const float* __restrict__ W3, const float* __restrict__ B3,
    const float* __restrict__ G1, const float* __restrict__ Be1,
    const float* __restrict__ M1, const float* __restrict__ V1,
    const float* __restrict__ G2, const float* __restrict__ Be2,
    const float* __restrict__ M2, const float* __restrict__ V2,
    const float* __restrict__ G3, const float* __restrict__ Be3,
    const float* __restrict__ M3, const float* __restrict__ V3,
    unsigned short* __restrict__ W1bf, float* __restrict__ b1f,
    float* __restrict__ w2q, float* __restrict__ b2t,
    unsigned short* __restrict__ WB)
{
    int idx = blockIdx.x * 256 + threadIdx.x;

    if (idx < C*J) {                       // W1bf[j][c]
        int j = idx >> 8, c = idx & 255;
        int p = j >> 2, d = j & 3;
        float s = G1[j] * rsqrtf(V1[j] + EPS);
        W1bf[idx] = f2bf(W1[(p*C + c)*D + d] * s);
        return;
    }
    idx -= C*J;
    if (idx < J) {
        float s = G1[idx] * rsqrtf(V1[idx] + EPS);
        b1f[idx] = B1[idx] * s + Be1[idx] - M1[idx] * s;
        return;
    }
    idx -= J;
    if (idx < 9*D*D*P) {                   // w2q
        int do_ = idx & 3, p = (idx >> 2) & 31;
        int r2 = idx >> 7, di = r2 & 3, k9 = r2 >> 2;
        int j = p*4 + do_;
        float s = G2[j] * rsqrtf(V2[j] + EPS);
        w2q[idx] = W2[((p*9 + k9)*4 + di)*4 + do_] * s;
        return;
    }
    idx -= 9*D*D*P;
    if (idx < J) {                         // b2t[do][p]
        int do_ = idx >> 5, p = idx & 31;
        int j = p*4 + do_;
        float s = G2[j] * rsqrtf(V2[j] + EPS);
        b2t[idx] = B2[j] * s + Be2[j] - M2[j] * s;
        return;
    }
    idx -= J;
    if (idx < P*C*8) {                     // WB[p][c][s]
        int s8 = idx & 7;
        int c = (idx >> 3) & 255;
        int p = idx >> 11;
        float sc = G3[p*C + c] * rsqrtf(V3[p*C + c] + EPS);
        float v = 0.f;
        if (s8 < 4)       v = W3[(p*D + s8)*C + c] * sc;
        else if (s8 == 4) v = B3[p*C + c] * sc + Be3[p*C + c] - M3[p*C + c] * sc;
        WB[idx] = f2bf(v);
        return;
    }
}

// ---------------------------------------------------------------------------
// Stage 1 (MFMA): h1[n][j] = relu( sum_c W1bf[j][c]*x[n][c] + b1f[j] ), bf16 out.
// D[j][n] = A(W)·B(x). Block: 4 waves, wave = j-range 32 (A-frags in regs),
// block n-tile = 32 staged once in XOR-swizzled LDS (full K resident).
// ---------------------------------------------------------------------------
__global__ __launch_bounds__(256) void stage1(
    const float* __restrict__ x, const unsigned short* __restrict__ W1bf,
    const float* __restrict__ b1f, unsigned short* __restrict__ h1)
{
    __shared__ unsigned short xs[32*256];   // row n, 32 groups of 8; group g stored at g^(n&7)

    const int tid = threadIdx.x;
    const int n0 = blockIdx.x * 32;
    const int wid = tid >> 6, l = tid & 63, l15 = l & 15, quad = l >> 4;
    const int j0w = wid * 32;

    // A-frags (W): 2 j-frags x 8 k-chunks, registers
    union bu { uint4 u; bf16x8_t v; };
    bu aw[2][8];
#pragma unroll
    for (int jf = 0; jf < 2; ++jf) {
        int row = j0w + jf*16 + l15;
#pragma unroll
        for (int kc = 0; kc < 8; ++kc)
            aw[jf][kc].u = *(const uint4*)&W1bf[row*C + kc*32 + quad*8];
    }

    // stage x tile: 32 rows x 256 cols, fp32 -> bf16, XOR-swizzled
#pragma unroll
    for (int it = 0; it < 4; ++it) {
        int row = tid >> 3;
        int g = (tid & 7) + it*8;
        const float* xp = &x[(size_t)(n0 + row) * C + g*8];
        float4 v0 = *(const float4*)xp;
        float4 v1 = *(const float4*)(xp + 4);
        uint2 p0 = pack4_trunc(v0), p1 = pack4_trunc(v1);
        uint4 st; st.x = p0.x; st.y = p0.y; st.z = p1.x; st.w = p1.y;
        *(uint4*)&xs[row*256 + ((g ^ (row & 7)) * 8)] = st;
    }
    __syncthreads();

    f32x4_t acc[2][2];
#pragma unroll
    for (int jf = 0; jf < 2; ++jf)
#pragma unroll
        for (int nf = 0; nf < 2; ++nf) acc[jf][nf] = (f32x4_t){0.f,0.f,0.f,0.f};

#pragma unroll
    for (int kc = 0; kc < 8; ++kc) {
#pragma unroll
        for (int nf = 0; nf < 2; ++nf) {
            int row = nf*16 + l15;
            int g = (kc*4 + quad) ^ (row & 7);
            bf16x8_t b = *(const bf16x8_t*)&xs[row*256 + g*8];
            acc[0][nf] = __builtin_amdgcn_mfma_f32_16x16x32_bf16(aw[0][kc].v, b, acc[0][nf], 0, 0, 0);
            acc[1][nf] = __builtin_amdgcn_mfma_f32_16x16x32_bf16(aw[1][kc].v, b, acc[1][nf], 0, 0, 0);
        }
    }

    // epilogue: D row = j = j0w + jf*16 + quad*4 + r ; col = n = n0 + nf*16 + l15
#pragma unroll
    for (int jf = 0; jf < 2; ++jf) {
        int jb = j0w + jf*16 + quad*4;
        float4 bias = *(const float4*)&b1f[jb];
#pragma unroll
        for (int nf = 0; nf < 2; ++nf) {
            int n = n0 + nf*16 + l15;
            float v0 = fmaxf(acc[jf][nf][0] + bias.x, 0.f);
            float v1 = fmaxf(acc[jf][nf][1] + bias.y, 0.f);
            float v2 = fmaxf(acc[jf][nf][2] + bias.z, 0.f);
            float v3 = fmaxf(acc[jf][nf][3] + bias.w, 0.f);
            uint2 o;
            o.x = (unsigned int)f2bf(v0) | ((unsigned int)f2bf(v1) << 16);
            o.y = (unsigned int)f2bf(v2) | ((unsigned int)f2bf(v3) << 16);
            *(uint2*)&h1[(size_t)n * J + jb] = o;
        }
    }
}

// ---------------------------------------------------------------------------
// Stage 2: grouped 3x3 conv (32 groups of 4->4), SAME, +bias, ReLU. bf16 in/out.
// One thread per (n,p). Weights in LDS p-major: lane-p reads are conflict-free
// float4 per (k9, di).
// ---------------------------------------------------------------------------
__global__ __launch_bounds__(256) void stage2(
    const unsigned short* __restrict__ h1,
    const float* __restrict__ w2q, const float* __restrict__ b2t,
    unsigned short* __restrict__ h2)
{
    __shared__ float ws[9*16*32];    // 4608 floats, [(k9*4+di)*128 + p*4 + do]
    __shared__ float bs[128];        // [do*32 + p]

    const int tid = threadIdx.x;
    for (int i = tid; i < 4608; i += 256) ws[i] = w2q[i];
    if (tid < 128) bs[tid] = b2t[tid];
    __syncthreads();

    const int t = blockIdx.x * 256 + tid;
    const int p = t & 31;
    const int n = t >> 5;
    const int w = n % WW;
    const int h = (n / WW) % HH;
    const int b = n / (HH*WW);

    float a0 = bs[p], a1 = bs[32 + p], a2 = bs[64 + p], a3 = bs[96 + p];

#pragma unroll
    for (int ky = 0; ky < 3; ++ky) {
        int yy = h + ky - 1;
        if (yy < 0 || yy >= HH) continue;
#pragma unroll
        for (int kx = 0; kx < 3; ++kx) {
            int xx = w + kx - 1;
            if (xx < 0 || xx >= WW) continue;
            uint2 hv = *(const uint2*)&h1[(size_t)((b*HH + yy)*WW + xx) * J + p*4];
            float f0 = __uint_as_float(hv.x << 16);
            float f1 = __uint_as_float(hv.x & 0xffff0000u);
            float f2 = __uint_as_float(hv.y << 16);
            float f3 = __uint_as_float(hv.y & 0xffff0000u);
            const float* wp = &ws[(ky*3 + kx) * 512 + p*4];
            float4 w0 = *(const float4*)&wp[0];     // di=0
            float4 w1 = *(const float4*)&wp[128];   // di=1
            float4 w2v = *(const float4*)&wp[256];  // di=2
            float4 w3v = *(const float4*)&wp[384];  // di=3
            a0 = fmaf(f0, w0.x, a0);  a1 = fmaf(f0, w0.y, a1);
            a2 = fmaf(f0, w0.z, a2);  a3 = fmaf(f0, w0.w, a3);
            a0 = fmaf(f1, w1.x, a0);  a1 = fmaf(f1, w1.y, a1);
            a2 = fmaf(f1, w1.z, a2);  a3 = fmaf(f1, w1.w, a3);
            a0 = fmaf(f2, w2v.x, a0); a1 = fmaf(f2, w2v.y, a1);
            a2 = fmaf(f2, w2v.z, a2); a3 = fmaf(f2, w2v.w, a3);
            a0 = fmaf(f3, w3v.x, a0); a1 = fmaf(f3, w3v.y, a1);
            a2 = fmaf(f3, w3v.z, a2); a3 = fmaf(f3, w3v.w, a3);
        }
    }
    uint2 o;
    o.x = (unsigned int)f2bf(fmaxf(a0, 0.f)) | ((unsigned int)f2bf(fmaxf(a1, 0.f)) << 16);
    o.y = (unsigned int)f2bf(fmaxf(a2, 0.f)) | ((unsigned int)f2bf(fmaxf(a3, 0.f)) << 16);
    *(uint2*)&h2[(size_t)n * J + p*4] = o;
}

// ---------------------------------------------------------------------------
// Stage 3 (MFMA): out[n][c] = relu( x[n][c] + sum_p relu( h2_p . W3_p + b3_p ) )
// v3: B-frags in LDS (compiler kept dropping register-resident B, r4/r6).
// Block = 64n x 64c quadrant, 4 waves (wave = 16c). LDS: h2 tile + WB slice
// (w-pairs + bias separated; quads 1-3 read a zero slot, same-addr broadcast).
// Loop p-outer (B-frag reused across 4 n-passes), relu-acc in C-layout regs.
// ---------------------------------------------------------------------------
#define S3_ROWSTRIDE 132   // shorts; A-read bank = (2*l15 + 2p) % 32 -> conflict-free
__global__ __launch_bounds__(256) void stage3(
    const unsigned short* __restrict__ h2,
    const unsigned short* __restrict__ WB,
    const float* __restrict__ x, float* __restrict__ out)
{
    __shared__ unsigned short h2s[64 * S3_ROWSTRIDE];   // 16,896 B
    __shared__ unsigned short wbw[P * 64 * 4];          // 16,384 B  [p][cl] -> w0..w3
    __shared__ unsigned short wbb[P * 64];              //  4,096 B  [p][cl] -> bias
    __shared__ unsigned short zz[8];                    //     16 B  zeros

    const int tid = threadIdx.x;
    const int bx = blockIdx.x;
    const int cchunk = bx & 3, nchunk = bx >> 2;
    const int wid = tid >> 6, l = tid & 63, l15 = l & 15, quad = l >> 4;
    const int cb = cchunk * 64;
    const int cl = wid*16 + l15;          // c-local within quadrant
    const int c = cb + cl;
    const int n0 = nchunk * 64;

    // stage h2 tile: 64 rows x 128 cols bf16 = 1024 uint4, 16 uint4/row
#pragma unroll
    for (int it = 0; it < 4; ++it) {
        int idx = it*256 + tid;
        int row = idx >> 4, col = (idx & 15) * 8;
        uint4 v = *(const uint4*)&h2[(size_t)(n0 + row) * J + col];
        *(uint4*)&h2s[row * S3_ROWSTRIDE + col] = v;
    }
    // stage WB slice: 32p x 64c entries of 16B -> split into w-pairs + bias
#pragma unroll
    for (int it = 0; it < 8; ++it) {
        int e = it*256 + tid;             // 2048 entries
        int p = e >> 6, ecl = e & 63;
        uint4 u = *(const uint4*)&WB[((size_t)p*C + cb + ecl)*8];
        *(uint2*)&wbw[(p*64 + ecl)*4] = make_uint2(u.x, u.y);
        wbb[p*64 + ecl] = (unsigned short)(u.z & 0xffffu);
    }
    if (tid < 8) zz[tid] = 0;
    __syncthreads();

    // lane-constant B addresses: quad 0 reads real data, quads 1-3 read zeros
    const unsigned short* bwp = (quad == 0) ? &wbw[cl*4] : &zz[0];
    const unsigned short* bbp = (quad == 0) ? &wbb[cl]   : &zz[0];
    const int stepw = (quad == 0) ? 64*4 : 0;   // shorts per p
    const int stepb = (quad == 0) ? 64   : 0;

    const f32x4_t zero = (f32x4_t){0.f, 0.f, 0.f, 0.f};
    f32x4_t acc[4];
#pragma unroll
    for (int i = 0; i < 4; ++i) acc[i] = zero;

#pragma unroll
    for (int p = 0; p < P; ++p) {
        union { unsigned int u[4]; bf16x8_t v; } bfr;
        uint2 w8 = *(const uint2*)(bwp + p*stepw);       // ds_read_b64
        bfr.u[0] = w8.x; bfr.u[1] = w8.y;
        bfr.u[2] = (unsigned int)bbp[p*stepb];           // ds_read_u16 -> {bias,0} @ k=4
        bfr.u[3] = 0u;
#pragma unroll
        for (int pass = 0; pass < 4; ++pass) {
            union { unsigned int u[4]; bf16x8_t v; } af;
            uint2 h4 = *(const uint2*)&h2s[(pass*16 + l15) * S3_ROWSTRIDE + p*4];
            af.u[0] = h4.x; af.u[1] = h4.y;
            af.u[2] = 0x3f80u;                           // A[k4] = 1.0 (bias lane)
            af.u[3] = 0u;
            f32x4_t z = __builtin_amdgcn_mfma_f32_16x16x32_bf16(af.v, bfr.v, zero, 0, 0, 0);
            acc[pass][0] += fmaxf(z[0], 0.f);
            acc[pass][1] += fmaxf(z[1], 0.f);
            acc[pass][2] += fmaxf(z[2], 0.f);
            acc[pass][3] += fmaxf(z[3], 0.f);
        }
    }

#pragma unroll
    for (int pass = 0; pass < 4; ++pass) {
#pragma unroll
        for (int r = 0; r < 4; ++r) {
            int n = n0 + pass*16 + quad*4 + r;
            float v = acc[pass][r] + x[(size_t)n * C + c];
            out[(size_t)n * C + c] = fmaxf(v, 0.f);
        }
    }
}

// ---------------------------------------------------------------------------
extern "C" void kernel_launch(void* const* d_in, const int* in_sizes, int n_in,
                              void* d_out, int out_size, void* d_ws, size_t ws_size,
                              hipStream_t stream) {
    const float* x  = (const float*)d_in[0];
    const float* W1 = (const float*)d_in[1];
    const float* B1 = (const float*)d_in[2];
    const float* W2 = (const float*)d_in[3];
    const float* B2 = (const float*)d_in[4];
    const float* W3 = (const float*)d_in[5];
    const float* B3 = (const float*)d_in[6];
    const float* G1 = (const float*)d_in[7];
    const float* Be1= (const float*)d_in[8];
    const float* M1 = (const float*)d_in[9];
    const float* V1 = (const float*)d_in[10];
    const float* G2 = (const float*)d_in[11];
    const float* Be2= (const float*)d_in[12];
    const float* M2 = (const float*)d_in[13];
    const float* V2 = (const float*)d_in[14];
    const float* G3 = (const float*)d_in[15];
    const float* Be3= (const float*)d_in[16];
    const float* M3 = (const float*)d_in[17];
    const float* V3 = (const float*)d_in[18];

    char* wsb = (char*)d_ws;
    unsigned short* h1   = (unsigned short*)(wsb + 0);          // 6,422,528 B
    unsigned short* h2   = (unsigned short*)(wsb + 6422528);    // 6,422,528 B
    unsigned short* W1bf = (unsigned short*)(wsb + 12845056);   // 65,536 B
    unsigned short* WB   = (unsigned short*)(wsb + 12910592);   // 131,072 B
    float*          w2q  = (float*)(wsb + 13041664);            // 18,432 B
    float*          b1f  = (float*)(wsb + 13060096);            // 512 B
    float*          b2t  = (float*)(wsb + 13060608);            // 512 B

    const int fold_tasks = C*J + J + 9*D*D*P + J + P*C*8;       // 103,168
    fold_params<<<(fold_tasks + 255)/256, 256, 0, stream>>>(
        W1, B1, W2, B2, W3, B3, G1, Be1, M1, V1, G2, Be2, M2, V2,
        G3, Be3, M3, V3, W1bf, b1f, w2q, b2t, WB);

    stage1<<<NPOS/32, 256, 0, stream>>>(x, W1bf, b1f, h1);
    stage2<<<(NPOS*P)/256, 256, 0, stream>>>(h1, w2q, b2t, h2);
    stage3<<<(NPOS/64)*4, 256, 0, stream>>>(h2, WB, x, (float*)d_out);
}

// Round 8
// 161.161 us; speedup vs baseline: 1.3927x; 1.0175x over previous
//
#include <hip/hip_runtime.h>

// Problem constants
#define BATCH 8
#define HH 56
#define WW 56
#define NPOS (BATCH*HH*WW)   // 25088
#define C 256
#define P 32
#define D 4
#define J 128
#define EPS 1e-3f

typedef __attribute__((ext_vector_type(8))) short bf16x8_t;
typedef __attribute__((ext_vector_type(4))) float f32x4_t;

__device__ __forceinline__ unsigned short f2bf(float f) {
    union { float f; unsigned int i; } v; v.f = f;
    unsigned int r = v.i + 0x7fffu + ((v.i >> 16) & 1u);   // RNE
    return (unsigned short)(r >> 16);
}
__device__ __forceinline__ uint2 pack4_trunc(float4 v) {
    uint2 r;
    r.x = __builtin_amdgcn_perm(__float_as_uint(v.y), __float_as_uint(v.x), 0x07060302u);
    r.y = __builtin_amdgcn_perm(__float_as_uint(v.w), __float_as_uint(v.z), 0x07060302u);
    return r;
}

// ---------------------------------------------------------------------------
// Fold BN into conv weights/biases (unchanged from r7).
// ---------------------------------------------------------------------------
__global__ __launch_bounds__(256) void fold_params(
    const float* __restrict__ W1, const float* __restrict__ B1,
    const float* __restrict__ W2, const float* __restrict__ B2,
    const float* __restrict__ W3, const float* __restrict__ B3,
    const float* __restrict__ G1, const float* __restrict__ Be1,
    const float* __restrict__ M1, const float* __restrict__ V1,
    const float* __restrict__ G2, const float* __restrict__ Be2,
    const float* __restrict__ M2, const float* __restrict__ V2,
    const float* __restrict__ G3, const float* __restrict__ Be3,
    const float* __restrict__ M3, const float* __restrict__ V3,
    unsigned short* __restrict__ W1bf, float* __restrict__ b1f,
    float* __restrict__ w2q, float* __restrict__ b2t,
    unsigned short* __restrict__ WB)
{
    int idx = blockIdx.x * 256 + threadIdx.x;

    if (idx < C*J) {                       // W1bf[j][c]
        int j = idx >> 8, c = idx & 255;
        int p = j >> 2, d = j & 3;
        float s = G1[j] * rsqrtf(V1[j] + EPS);
        W1bf[idx] = f2bf(W1[(p*C + c)*D + d] * s);
        return;
    }
    idx -= C*J;
    if (idx < J) {
        float s = G1[idx] * rsqrtf(V1[idx] + EPS);
        b1f[idx] = B1[idx] * s + Be1[idx] - M1[idx] * s;
        return;
    }
    idx -= J;
    if (idx < 9*D*D*P) {                   // w2q [(k9*4+di)*128 + p*4 + do]
        int do_ = idx & 3, p = (idx >> 2) & 31;
        int r2 = idx >> 7, di = r2 & 3, k9 = r2 >> 2;
        int j = p*4 + do_;
        float s = G2[j] * rsqrtf(V2[j] + EPS);
        w2q[idx] = W2[((p*9 + k9)*4 + di)*4 + do_] * s;
        return;
    }
    idx -= 9*D*D*P;
    if (idx < J) {                         // b2t[do][p]
        int do_ = idx >> 5, p = idx & 31;
        int j = p*4 + do_;
        float s = G2[j] * rsqrtf(V2[j] + EPS);
        b2t[idx] = B2[j] * s + Be2[j] - M2[j] * s;
        return;
    }
    idx -= J;
    if (idx < P*C*8) {                     // WB[p][c][s] = {w0..w3, bias, 0,0,0}
        int s8 = idx & 7;
        int c = (idx >> 3) & 255;
        int p = idx >> 11;
        float sc = G3[p*C + c] * rsqrtf(V3[p*C + c] + EPS);
        float v = 0.f;
        if (s8 < 4)       v = W3[(p*D + s8)*C + c] * sc;
        else if (s8 == 4) v = B3[p*C + c] * sc + Be3[p*C + c] - M3[p*C + c] * sc;
        WB[idx] = f2bf(v);
        return;
    }
}

// ---------------------------------------------------------------------------
// Fused stage1+stage2. Spatial tile: 4y x 8x interior, 6y x 10x halo (60 pos).
// Grid: 8 batch * 14 ybands * 7 xbands = 784 blocks, 256 thr.
// Phase A: x halo -> LDS bf16 (XOR-swizzled), zeros outside image.
// Phase B: s1 MFMA (W A-frags in regs from W1bf) -> h1 tile in LDS.
// Phase C: s2 grouped 3x3 from LDS h1 (per-tap global-coord validity) -> h2.
// ---------------------------------------------------------------------------
__global__ __launch_bounds__(256) void fused12(
    const float* __restrict__ x, const unsigned short* __restrict__ W1bf,
    const float* __restrict__ b1f, const float* __restrict__ w2q,
    const float* __restrict__ b2t, unsigned short* __restrict__ h2)
{
    __shared__ unsigned short xs[64*256];    // 32 KB halo tile (rows 60..63 zero)
    __shared__ unsigned short h1L[64*132];   // 16.9 KB  [pos][j], stride 132
    __shared__ float w2s[4608];              // 18.4 KB
    __shared__ float bs[128];
    __shared__ float b1s[128];

    const int tid = threadIdx.x;
    int bxx = blockIdx.x;
    const int xb = bxx % 7;  bxx /= 7;
    const int yb = bxx % 14; const int b = bxx / 14;
    const int wid = tid >> 6, l = tid & 63, l15 = l & 15, quad = l >> 4;
    const int j0w = wid * 32;

    // W1 A-frags (global, L2-hot) — issue early, overlap staging
    union bu { uint4 u; bf16x8_t v; };
    bu aw[2][8];
#pragma unroll
    for (int jf = 0; jf < 2; ++jf) {
        int row = j0w + jf*16 + l15;
#pragma unroll
        for (int kc = 0; kc < 8; ++kc)
            aw[jf][kc].u = *(const uint4*)&W1bf[row*C + kc*32 + quad*8];
    }

    // stage conv2 weights + biases
    for (int i = tid; i < 4608; i += 256) w2s[i] = w2q[i];
    if (tid < 128) { bs[tid] = b2t[tid]; b1s[tid] = b1f[tid]; }

    // Phase A: stage x halo (60 pos x 256 ch), fp32->bf16, XOR-swizzled
#pragma unroll
    for (int it = 0; it < 8; ++it) {
        int idx = it*256 + tid;              // 2048 tasks
        int pos = idx >> 5, g = idx & 31;
        uint4 st; st.x = 0u; st.y = 0u; st.z = 0u; st.w = 0u;
        if (pos < 60) {
            int hy = pos / 10, hx = pos - hy*10;
            int gy = yb*4 + hy - 1, gx = xb*8 + hx - 1;
            if (gy >= 0 && gy < HH && gx >= 0 && gx < WW) {
                const float* xp = &x[(size_t)((b*HH + gy)*WW + gx) * C + g*8];
                float4 v0 = *(const float4*)xp;
                float4 v1 = *(const float4*)(xp + 4);
                uint2 p0 = pack4_trunc(v0), p1 = pack4_trunc(v1);
                st.x = p0.x; st.y = p0.y; st.z = p1.x; st.w = p1.y;
            }
        }
        *(uint4*)&xs[pos*256 + ((g ^ (pos & 7)) * 8)] = st;
    }
    __syncthreads();

    // Phase B: s1 GEMM -> h1L. 4 m-tiles of 16 pos; wave = 32 j.
#pragma unroll
    for (int mt = 0; mt < 4; ++mt) {
        const int row = mt*16 + l15;         // pos (B col)
        f32x4_t acc0 = (f32x4_t){0.f,0.f,0.f,0.f};
        f32x4_t acc1 = (f32x4_t){0.f,0.f,0.f,0.f};
#pragma unroll
        for (int kc = 0; kc < 8; ++kc) {
            int g = (kc*4 + quad) ^ (row & 7);
            bf16x8_t bb = *(const bf16x8_t*)&xs[row*256 + g*8];
            acc0 = __builtin_amdgcn_mfma_f32_16x16x32_bf16(aw[0][kc].v, bb, acc0, 0, 0, 0);
            acc1 = __builtin_amdgcn_mfma_f32_16x16x32_bf16(aw[1][kc].v, bb, acc1, 0, 0, 0);
        }
#pragma unroll
        for (int jf = 0; jf < 2; ++jf) {
            const f32x4_t a = jf ? acc1 : acc0;
            int jb = j0w + jf*16 + quad*4;
            float4 bias = *(const float4*)&b1s[jb];
            float v0 = fmaxf(a[0] + bias.x, 0.f);
            float v1 = fmaxf(a[1] + bias.y, 0.f);
            float v2 = fmaxf(a[2] + bias.z, 0.f);
            float v3 = fmaxf(a[3] + bias.w, 0.f);
            uint2 o;
            o.x = (unsigned int)f2bf(v0) | ((unsigned int)f2bf(v1) << 16);
            o.y = (unsigned int)f2bf(v2) | ((unsigned int)f2bf(v3) << 16);
            *(uint2*)&h1L[row*132 + jb] = o;   // pos = D col = l15-row; j = D row
        }
    }
    __syncthreads();

    // Phase C: s2 grouped conv from LDS. thread -> (n_local, p), 4 pairs.
    const int p = tid & 31;
    const float ba0 = bs[p], ba1 = bs[32+p], ba2 = bs[64+p], ba3 = bs[96+p];
#pragma unroll
    for (int i = 0; i < 4; ++i) {
        const int nl = (tid >> 5) + i*8;     // 0..31
        const int iy = nl >> 3, ix = nl & 7;
        const int gy = yb*4 + iy, gx = xb*8 + ix;
        float a0 = ba0, a1 = ba1, a2 = ba2, a3 = ba3;
#pragma unroll
        for (int ky = 0; ky < 3; ++ky) {
            int yy = gy + ky - 1;
            if (yy < 0 || yy >= HH) continue;
#pragma unroll
            for (int kx = 0; kx < 3; ++kx) {
                int xx = gx + kx - 1;
                if (xx < 0 || xx >= WW) continue;
                int pos = (iy + ky)*10 + (ix + kx);
                uint2 hv = *(const uint2*)&h1L[pos*132 + p*4];
                float f0 = __uint_as_float(hv.x << 16);
                float f1 = __uint_as_float(hv.x & 0xffff0000u);
                float f2 = __uint_as_float(hv.y << 16);
                float f3 = __uint_as_float(hv.y & 0xffff0000u);
                const float* wp = &w2s[(ky*3 + kx) * 512 + p*4];
                float4 w0 = *(const float4*)&wp[0];
                float4 w1 = *(const float4*)&wp[128];
                float4 w2v = *(const float4*)&wp[256];
                float4 w3v = *(const float4*)&wp[384];
                a0 = fmaf(f0, w0.x, a0);  a1 = fmaf(f0, w0.y, a1);
                a2 = fmaf(f0, w0.z, a2);  a3 = fmaf(f0, w0.w, a3);
                a0 = fmaf(f1, w1.x, a0);  a1 = fmaf(f1, w1.y, a1);
                a2 = fmaf(f1, w1.z, a2);  a3 = fmaf(f1, w1.w, a3);
                a0 = fmaf(f2, w2v.x, a0); a1 = fmaf(f2, w2v.y, a1);
                a2 = fmaf(f2, w2v.z, a2); a3 = fmaf(f2, w2v.w, a3);
                a0 = fmaf(f3, w3v.x, a0); a1 = fmaf(f3, w3v.y, a1);
                a2 = fmaf(f3, w3v.z, a2); a3 = fmaf(f3, w3v.w, a3);
            }
        }
        uint2 o;
        o.x = (unsigned int)f2bf(fmaxf(a0, 0.f)) | ((unsigned int)f2bf(fmaxf(a1, 0.f)) << 16);
        o.y = (unsigned int)f2bf(fmaxf(a2, 0.f)) | ((unsigned int)f2bf(fmaxf(a3, 0.f)) << 16);
        int n = (b*HH + gy)*WW + gx;
        *(uint2*)&h2[(size_t)n * J + p*4] = o;
    }
}

// ---------------------------------------------------------------------------
// Stage 3 (MFMA): out[n][c] = relu( x[n][c] + sum_p relu( h2_p . W3_p + b3_p ) )
// r7 structure, leaner: ONE ds_read_b128 per p = full B-frag (w0..3 + bias@k4);
// A-frags read in p-pairs (one b128 serves p and p+1). 3 blocks/CU.
// ---------------------------------------------------------------------------
#define S3_STRIDE 136   // shorts; 272 B rows, 16B-aligned; 2-way banks only
__global__ __launch_bounds__(256, 3) void stage3(
    const unsigned short* __restrict__ h2,
    const unsigned short* __restrict__ WB,
    const float* __restrict__ x, float* __restrict__ out)
{
    __shared__ unsigned short h2s[64 * S3_STRIDE];   // 17,408 B
    __shared__ unsigned short wbf[P * 64 * 8];       // 32,768 B  [p][cl][8]
    __shared__ unsigned short zz[8];

    const int tid = threadIdx.x;
    const int bx = blockIdx.x;
    const int cchunk = bx & 3, nchunk = bx >> 2;
    const int wid = tid >> 6, l = tid & 63, l15 = l & 15, quad = l >> 4;
    const int cb = cchunk * 64;
    const int cl = wid*16 + l15;
    const int c = cb + cl;
    const int n0 = nchunk * 64;

    // stage h2 tile: 64 x 128 bf16 = 1024 uint4
#pragma unroll
    for (int it = 0; it < 4; ++it) {
        int idx = it*256 + tid;
        int row = idx >> 4, col = (idx & 15) * 8;
        uint4 v = *(const uint4*)&h2[(size_t)(n0 + row) * J + col];
        *(uint4*)&h2s[row * S3_STRIDE + col] = v;
    }
    // stage WB slice: [p][cl] 16B entries (already {w0..3,bias,0,0,0})
#pragma unroll
    for (int it = 0; it < 8; ++it) {
        int e = it*256 + tid;                // 2048 entries
        int p = e >> 6, ecl = e & 63;
        uint4 u = *(const uint4*)&WB[((size_t)(p*C + cb + ecl)) * 8];
        *(uint4*)&wbf[(p*64 + ecl) * 8] = u;
    }
    if (tid < 8) zz[tid] = 0;
    __syncthreads();

    const unsigned short* bp = (quad == 0) ? &wbf[cl*8] : &zz[0];
    const int pstep = (quad == 0) ? 512 : 0;   // shorts per p

    const f32x4_t zero = (f32x4_t){0.f, 0.f, 0.f, 0.f};
    f32x4_t acc[4];
#pragma unroll
    for (int i = 0; i < 4; ++i) acc[i] = zero;
    const unsigned int one = 0x3f80u;          // bf16 1.0 in low half

#pragma unroll
    for (int p = 0; p < P; p += 2) {
        union { uint4 u; bf16x8_t v; } B0, B1;
        B0.u = *(const uint4*)(bp + p*pstep);
        B1.u = *(const uint4*)(bp + (p+1)*pstep);
#pragma unroll
        for (int pass = 0; pass < 4; ++pass) {
            uint4 h8 = *(const uint4*)&h2s[(pass*16 + l15) * S3_STRIDE + p*4];
            union { unsigned int u[4]; bf16x8_t v; } A0, A1;
            A0.u[0] = h8.x; A0.u[1] = h8.y; A0.u[2] = one; A0.u[3] = 0u;
            A1.u[0] = h8.z; A1.u[1] = h8.w; A1.u[2] = one; A1.u[3] = 0u;
            f32x4_t z0 = __builtin_amdgcn_mfma_f32_16x16x32_bf16(A0.v, B0.v, zero, 0, 0, 0);
            f32x4_t z1 = __builtin_amdgcn_mfma_f32_16x16x32_bf16(A1.v, B1.v, zero, 0, 0, 0);
#pragma unroll
            for (int r = 0; r < 4; ++r)
                acc[pass][r] += fmaxf(z0[r], 0.f) + fmaxf(z1[r], 0.f);
        }
    }

#pragma unroll
    for (int pass = 0; pass < 4; ++pass) {
#pragma unroll
        for (int r = 0; r < 4; ++r) {
            int n = n0 + pass*16 + quad*4 + r;
            float v = acc[pass][r] + x[(size_t)n * C + c];
            out[(size_t)n * C + c] = fmaxf(v, 0.f);
        }
    }
}

// ---------------------------------------------------------------------------
extern "C" void kernel_launch(void* const* d_in, const int* in_sizes, int n_in,
                              void* d_out, int out_size, void* d_ws, size_t ws_size,
                              hipStream_t stream) {
    const float* x  = (const float*)d_in[0];
    const float* W1 = (const float*)d_in[1];
    const float* B1 = (const float*)d_in[2];
    const float* W2 = (const float*)d_in[3];
    const float* B2 = (const float*)d_in[4];
    const float* W3 = (const float*)d_in[5];
    const float* B3 = (const float*)d_in[6];
    const float* G1 = (const float*)d_in[7];
    const float* Be1= (const float*)d_in[8];
    const float* M1 = (const float*)d_in[9];
    const float* V1 = (const float*)d_in[10];
    const float* G2 = (const float*)d_in[11];
    const float* Be2= (const float*)d_in[12];
    const float* M2 = (const float*)d_in[13];
    const float* V2 = (const float*)d_in[14];
    const float* G3 = (const float*)d_in[15];
    const float* Be3= (const float*)d_in[16];
    const float* M3 = (const float*)d_in[17];
    const float* V3 = (const float*)d_in[18];

    char* wsb = (char*)d_ws;
    unsigned short* h2   = (unsigned short*)(wsb + 0);          // 6,422,528 B
    unsigned short* W1bf = (unsigned short*)(wsb + 6422528);    // 65,536 B
    unsigned short* WB   = (unsigned short*)(wsb + 6488064);    // 131,072 B
    float*          w2q  = (float*)(wsb + 6619136);             // 18,432 B
    float*          b1f  = (float*)(wsb + 6637568);             // 512 B
    float*          b2t  = (float*)(wsb + 6638080);             // 512 B

    const int fold_tasks = C*J + J + 9*D*D*P + J + P*C*8;       // 103,168
    fold_params<<<(fold_tasks + 255)/256, 256, 0, stream>>>(
        W1, B1, W2, B2, W3, B3, G1, Be1, M1, V1, G2, Be2, M2, V2,
        G3, Be3, M3, V3, W1bf, b1f, w2q, b2t, WB);

    fused12<<<8*14*7, 256, 0, stream>>>(x, W1bf, b1f, w2q, b2t, h2);
    stage3<<<(NPOS/64)*4, 256, 0, stream>>>(h2, WB, x, (float*)d_out);
}

// Round 9
// 161.089 us; speedup vs baseline: 1.3933x; 1.0004x over previous
//
#include <hip/hip_runtime.h>

// Problem constants
#define BATCH 8
#define HH 56
#define WW 56
#define NPOS (BATCH*HH*WW)   // 25088
#define C 256
#define P 32
#define D 4
#define J 128
#define EPS 1e-3f

typedef __attribute__((ext_vector_type(8))) short bf16x8_t;
typedef __attribute__((ext_vector_type(4))) float f32x4_t;

__device__ __forceinline__ unsigned short f2bf(float f) {
    union { float f; unsigned int i; } v; v.f = f;
    unsigned int r = v.i + 0x7fffu + ((v.i >> 16) & 1u);   // RNE
    return (unsigned short)(r >> 16);
}
__device__ __forceinline__ uint2 pack4_trunc(float4 v) {
    uint2 r;
    r.x = __builtin_amdgcn_perm(__float_as_uint(v.y), __float_as_uint(v.x), 0x07060302u);
    r.y = __builtin_amdgcn_perm(__float_as_uint(v.w), __float_as_uint(v.z), 0x07060302u);
    return r;
}

// ---------------------------------------------------------------------------
// Fold BN into conv weights/biases (unchanged from r7/r8).
// ---------------------------------------------------------------------------
__global__ __launch_bounds__(256) void fold_params(
    const float* __restrict__ W1, const float* __restrict__ B1,
    const float* __restrict__ W2, const float* __restrict__ B2,
    const float* __restrict__ W3, const float* __restrict__ B3,
    const float* __restrict__ G1, const float* __restrict__ Be1,
    const float* __restrict__ M1, const float* __restrict__ V1,
    const float* __restrict__ G2, const float* __restrict__ Be2,
    const float* __restrict__ M2, const float* __restrict__ V2,
    const float* __restrict__ G3, const float* __restrict__ Be3,
    const float* __restrict__ M3, const float* __restrict__ V3,
    unsigned short* __restrict__ W1bf, float* __restrict__ b1f,
    float* __restrict__ w2q, float* __restrict__ b2t,
    unsigned short* __restrict__ WB)
{
    int idx = blockIdx.x * 256 + threadIdx.x;

    if (idx < C*J) {                       // W1bf[j][c]
        int j = idx >> 8, c = idx & 255;
        int p = j >> 2, d = j & 3;
        float s = G1[j] * rsqrtf(V1[j] + EPS);
        W1bf[idx] = f2bf(W1[(p*C + c)*D + d] * s);
        return;
    }
    idx -= C*J;
    if (idx < J) {
        float s = G1[idx] * rsqrtf(V1[idx] + EPS);
        b1f[idx] = B1[idx] * s + Be1[idx] - M1[idx] * s;
        return;
    }
    idx -= J;
    if (idx < 9*D*D*P) {                   // w2q [(k9*4+di)*128 + p*4 + do]
        int do_ = idx & 3, p = (idx >> 2) & 31;
        int r2 = idx >> 7, di = r2 & 3, k9 = r2 >> 2;
        int j = p*4 + do_;
        float s = G2[j] * rsqrtf(V2[j] + EPS);
        w2q[idx] = W2[((p*9 + k9)*4 + di)*4 + do_] * s;
        return;
    }
    idx -= 9*D*D*P;
    if (idx < J) {                         // b2t[do][p]
        int do_ = idx >> 5, p = idx & 31;
        int j = p*4 + do_;
        float s = G2[j] * rsqrtf(V2[j] + EPS);
        b2t[idx] = B2[j] * s + Be2[j] - M2[j] * s;
        return;
    }
    idx -= J;
    if (idx < P*C*8) {                     // WB[p][c][s] = {w0..w3, bias, 0,0,0}
        int s8 = idx & 7;
        int c = (idx >> 3) & 255;
        int p = idx >> 11;
        float sc = G3[p*C + c] * rsqrtf(V3[p*C + c] + EPS);
        float v = 0.f;
        if (s8 < 4)       v = W3[(p*D + s8)*C + c] * sc;
        else if (s8 == 4) v = B3[p*C + c] * sc + Be3[p*C + c] - M3[p*C + c] * sc;
        WB[idx] = f2bf(v);
        return;
    }
}

// ---------------------------------------------------------------------------
// Fused stage1+stage2. Spatial tile: 4y x 8x interior, 6y x 10x halo (60 pos).
// Grid: 8*14*7 = 784 blocks, 256 thr.
// Phase A: x halo -> LDS bf16 (XOR-swizzled), zeros outside image.
// Phase B: s1 MFMA -> h1L; OOB halo positions stored as ZERO (mask) so the
//          SAME-pad conv needs no tap branches.
// Phase C: s2 grouped 3x3, TAP-OUTER: weights hoisted to regs once per tap
//          (36 b128 instead of 144), positions inner, branch-free.
// ---------------------------------------------------------------------------
__global__ __launch_bounds__(256) void fused12(
    const float* __restrict__ x, const unsigned short* __restrict__ W1bf,
    const float* __restrict__ b1f, const float* __restrict__ w2q,
    const float* __restrict__ b2t, unsigned short* __restrict__ h2)
{
    __shared__ unsigned short xs[64*256];    // 32 KB halo tile (rows 60..63 zero)
    __shared__ unsigned short h1L[64*132];   // 16.9 KB  [pos][j], stride 132
    __shared__ float w2s[4608];              // 18.4 KB
    __shared__ float bs[128];
    __shared__ float b1s[128];

    const int tid = threadIdx.x;
    int bxx = blockIdx.x;
    const int xb = bxx % 7;  bxx /= 7;
    const int yb = bxx % 14; const int b = bxx / 14;
    const int wid = tid >> 6, l = tid & 63, l15 = l & 15, quad = l >> 4;
    const int j0w = wid * 32;

    // W1 A-frags (global, L2-hot)
    union bu { uint4 u; bf16x8_t v; };
    bu aw[2][8];
#pragma unroll
    for (int jf = 0; jf < 2; ++jf) {
        int row = j0w + jf*16 + l15;
#pragma unroll
        for (int kc = 0; kc < 8; ++kc)
            aw[jf][kc].u = *(const uint4*)&W1bf[row*C + kc*32 + quad*8];
    }

    // stage conv2 weights + biases
    for (int i = tid; i < 4608; i += 256) w2s[i] = w2q[i];
    if (tid < 128) { bs[tid] = b2t[tid]; b1s[tid] = b1f[tid]; }

    // Phase A: stage x halo (60 pos x 256 ch), fp32->bf16, XOR-swizzled
#pragma unroll
    for (int it = 0; it < 8; ++it) {
        int idx = it*256 + tid;              // 2048 tasks
        int pos = idx >> 5, g = idx & 31;
        uint4 st; st.x = 0u; st.y = 0u; st.z = 0u; st.w = 0u;
        if (pos < 60) {
            int hy = pos / 10, hx = pos - hy*10;
            int gy = yb*4 + hy - 1, gx = xb*8 + hx - 1;
            if (gy >= 0 && gy < HH && gx >= 0 && gx < WW) {
                const float* xp = &x[(size_t)((b*HH + gy)*WW + gx) * C + g*8];
                float4 v0 = *(const float4*)xp;
                float4 v1 = *(const float4*)(xp + 4);
                uint2 p0 = pack4_trunc(v0), p1 = pack4_trunc(v1);
                st.x = p0.x; st.y = p0.y; st.z = p1.x; st.w = p1.y;
            }
        }
        *(uint4*)&xs[pos*256 + ((g ^ (pos & 7)) * 8)] = st;
    }
    __syncthreads();

    // Phase B: s1 GEMM -> h1L (OOB positions zeroed via mask).
#pragma unroll
    for (int mt = 0; mt < 4; ++mt) {
        const int row = mt*16 + l15;         // halo pos (B col)
        // validity of this halo position (zero-pad SAME conv)
        int hy = (row * 205) >> 11;          // row/10 for row in [0,64)
        int hx = row - hy*10;
        int gy = yb*4 + hy - 1, gx = xb*8 + hx - 1;
        unsigned mask = (row < 60 && gy >= 0 && gy < HH && gx >= 0 && gx < WW)
                        ? 0xFFFFFFFFu : 0u;
        f32x4_t acc0 = (f32x4_t){0.f,0.f,0.f,0.f};
        f32x4_t acc1 = (f32x4_t){0.f,0.f,0.f,0.f};
#pragma unroll
        for (int kc = 0; kc < 8; ++kc) {
            int g = (kc*4 + quad) ^ (row & 7);
            bf16x8_t bb = *(const bf16x8_t*)&xs[row*256 + g*8];
            acc0 = __builtin_amdgcn_mfma_f32_16x16x32_bf16(aw[0][kc].v, bb, acc0, 0, 0, 0);
            acc1 = __builtin_amdgcn_mfma_f32_16x16x32_bf16(aw[1][kc].v, bb, acc1, 0, 0, 0);
        }
#pragma unroll
        for (int jf = 0; jf < 2; ++jf) {
            const f32x4_t a = jf ? acc1 : acc0;
            int jb = j0w + jf*16 + quad*4;
            float4 bias = *(const float4*)&b1s[jb];
            float v0 = fmaxf(a[0] + bias.x, 0.f);
            float v1 = fmaxf(a[1] + bias.y, 0.f);
            float v2 = fmaxf(a[2] + bias.z, 0.f);
            float v3 = fmaxf(a[3] + bias.w, 0.f);
            uint2 o;
            o.x = ((unsigned int)f2bf(v0) | ((unsigned int)f2bf(v1) << 16)) & mask;
            o.y = ((unsigned int)f2bf(v2) | ((unsigned int)f2bf(v3) << 16)) & mask;
            *(uint2*)&h1L[row*132 + jb] = o;
        }
    }
    __syncthreads();

    // Phase C: tap-outer grouped conv. thread -> p = tid&31, slot = tid>>5.
    const int p = tid & 31;
    const int slot = tid >> 5;               // 0..7
    float acc[4][4];
#pragma unroll
    for (int i = 0; i < 4; ++i) {
        acc[i][0] = bs[p]; acc[i][1] = bs[32+p];
        acc[i][2] = bs[64+p]; acc[i][3] = bs[96+p];
    }
#pragma unroll
    for (int ky = 0; ky < 3; ++ky) {
#pragma unroll
        for (int kx = 0; kx < 3; ++kx) {
            const float* wp = &w2s[(ky*3 + kx) * 512 + p*4];
            float4 w0 = *(const float4*)&wp[0];     // di=0
            float4 w1 = *(const float4*)&wp[128];   // di=1
            float4 w2v = *(const float4*)&wp[256];  // di=2
            float4 w3v = *(const float4*)&wp[384];  // di=3
#pragma unroll
            for (int i = 0; i < 4; ++i) {
                int nl = slot + i*8;                 // interior pos 0..31
                int hp = ((nl >> 3) + ky)*10 + (nl & 7) + kx;
                uint2 hv = *(const uint2*)&h1L[hp*132 + p*4];
                float f0 = __uint_as_float(hv.x << 16);
                float f1 = __uint_as_float(hv.x & 0xffff0000u);
                float f2 = __uint_as_float(hv.y << 16);
                float f3 = __uint_as_float(hv.y & 0xffff0000u);
                acc[i][0] = fmaf(f0, w0.x, acc[i][0]);  acc[i][1] = fmaf(f0, w0.y, acc[i][1]);
                acc[i][2] = fmaf(f0, w0.z, acc[i][2]);  acc[i][3] = fmaf(f0, w0.w, acc[i][3]);
                acc[i][0] = fmaf(f1, w1.x, acc[i][0]);  acc[i][1] = fmaf(f1, w1.y, acc[i][1]);
                acc[i][2] = fmaf(f1, w1.z, acc[i][2]);  acc[i][3] = fmaf(f1, w1.w, acc[i][3]);
                acc[i][0] = fmaf(f2, w2v.x, acc[i][0]); acc[i][1] = fmaf(f2, w2v.y, acc[i][1]);
                acc[i][2] = fmaf(f2, w2v.z, acc[i][2]); acc[i][3] = fmaf(f2, w2v.w, acc[i][3]);
                acc[i][0] = fmaf(f3, w3v.x, acc[i][0]); acc[i][1] = fmaf(f3, w3v.y, acc[i][1]);
                acc[i][2] = fmaf(f3, w3v.z, acc[i][2]); acc[i][3] = fmaf(f3, w3v.w, acc[i][3]);
            }
        }
    }
#pragma unroll
    for (int i = 0; i < 4; ++i) {
        int nl = slot + i*8;
        int gy = yb*4 + (nl >> 3), gx = xb*8 + (nl & 7);
        uint2 o;
        o.x = (unsigned int)f2bf(fmaxf(acc[i][0], 0.f)) |
              ((unsigned int)f2bf(fmaxf(acc[i][1], 0.f)) << 16);
        o.y = (unsigned int)f2bf(fmaxf(acc[i][2], 0.f)) |
              ((unsigned int)f2bf(fmaxf(acc[i][3], 0.f)) << 16);
        int n = (b*HH + gy)*WW + gx;
        *(uint2*)&h2[(size_t)n * J + p*4] = o;
    }
}

// ---------------------------------------------------------------------------
// Stage 3 (unchanged from r8).
// ---------------------------------------------------------------------------
#define S3_STRIDE 136   // shorts; 272 B rows, 16B-aligned; 2-way banks only
__global__ __launch_bounds__(256, 3) void stage3(
    const unsigned short* __restrict__ h2,
    const unsigned short* __restrict__ WB,
    const float* __restrict__ x, float* __restrict__ out)
{
    __shared__ unsigned short h2s[64 * S3_STRIDE];   // 17,408 B
    __shared__ unsigned short wbf[P * 64 * 8];       // 32,768 B  [p][cl][8]
    __shared__ unsigned short zz[8];

    const int tid = threadIdx.x;
    const int bx = blockIdx.x;
    const int cchunk = bx & 3, nchunk = bx >> 2;
    const int wid = tid >> 6, l = tid & 63, l15 = l & 15, quad = l >> 4;
    const int cb = cchunk * 64;
    const int cl = wid*16 + l15;
    const int c = cb + cl;
    const int n0 = nchunk * 64;

#pragma unroll
    for (int it = 0; it < 4; ++it) {
        int idx = it*256 + tid;
        int row = idx >> 4, col = (idx & 15) * 8;
        uint4 v = *(const uint4*)&h2[(size_t)(n0 + row) * J + col];
        *(uint4*)&h2s[row * S3_STRIDE + col] = v;
    }
#pragma unroll
    for (int it = 0; it < 8; ++it) {
        int e = it*256 + tid;                // 2048 entries
        int p = e >> 6, ecl = e & 63;
        uint4 u = *(const uint4*)&WB[((size_t)(p*C + cb + ecl)) * 8];
        *(uint4*)&wbf[(p*64 + ecl) * 8] = u;
    }
    if (tid < 8) zz[tid] = 0;
    __syncthreads();

    const unsigned short* bp = (quad == 0) ? &wbf[cl*8] : &zz[0];
    const int pstep = (quad == 0) ? 512 : 0;   // shorts per p

    const f32x4_t zero = (f32x4_t){0.f, 0.f, 0.f, 0.f};
    f32x4_t acc[4];
#pragma unroll
    for (int i = 0; i < 4; ++i) acc[i] = zero;
    const unsigned int one = 0x3f80u;          // bf16 1.0 in low half

#pragma unroll
    for (int p = 0; p < P; p += 2) {
        union { uint4 u; bf16x8_t v; } B0, B1;
        B0.u = *(const uint4*)(bp + p*pstep);
        B1.u = *(const uint4*)(bp + (p+1)*pstep);
#pragma unroll
        for (int pass = 0; pass < 4; ++pass) {
            uint4 h8 = *(const uint4*)&h2s[(pass*16 + l15) * S3_STRIDE + p*4];
            union { unsigned int u[4]; bf16x8_t v; } A0, A1;
            A0.u[0] = h8.x; A0.u[1] = h8.y; A0.u[2] = one; A0.u[3] = 0u;
            A1.u[0] = h8.z; A1.u[1] = h8.w; A1.u[2] = one; A1.u[3] = 0u;
            f32x4_t z0 = __builtin_amdgcn_mfma_f32_16x16x32_bf16(A0.v, B0.v, zero, 0, 0, 0);
            f32x4_t z1 = __builtin_amdgcn_mfma_f32_16x16x32_bf16(A1.v, B1.v, zero, 0, 0, 0);
#pragma unroll
            for (int r = 0; r < 4; ++r)
                acc[pass][r] += fmaxf(z0[r], 0.f) + fmaxf(z1[r], 0.f);
        }
    }

#pragma unroll
    for (int pass = 0; pass < 4; ++pass) {
#pragma unroll
        for (int r = 0; r < 4; ++r) {
            int n = n0 + pass*16 + quad*4 + r;
            float v = acc[pass][r] + x[(size_t)n * C + c];
            out[(size_t)n * C + c] = fmaxf(v, 0.f);
        }
    }
}

// ---------------------------------------------------------------------------
extern "C" void kernel_launch(void* const* d_in, const int* in_sizes, int n_in,
                              void* d_out, int out_size, void* d_ws, size_t ws_size,
                              hipStream_t stream) {
    const float* x  = (const float*)d_in[0];
    const float* W1 = (const float*)d_in[1];
    const float* B1 = (const float*)d_in[2];
    const float* W2 = (const float*)d_in[3];
    const float* B2 = (const float*)d_in[4];
    const float* W3 = (const float*)d_in[5];
    const float* B3 = (const float*)d_in[6];
    const float* G1 = (const float*)d_in[7];
    const float* Be1= (const float*)d_in[8];
    const float* M1 = (const float*)d_in[9];
    const float* V1 = (const float*)d_in[10];
    const float* G2 = (const float*)d_in[11];
    const float* Be2= (const float*)d_in[12];
    const float* M2 = (const float*)d_in[13];
    const float* V2 = (const float*)d_in[14];
    const float* G3 = (const float*)d_in[15];
    const float* Be3= (const float*)d_in[16];
    const float* M3 = (const float*)d_in[17];
    const float* V3 = (const float*)d_in[18];

    char* wsb = (char*)d_ws;
    unsigned short* h2   = (unsigned short*)(wsb + 0);          // 6,422,528 B
    unsigned short* W1bf = (unsigned short*)(wsb + 6422528);    // 65,536 B
    unsigned short* WB   = (unsigned short*)(wsb + 6488064);    // 131,072 B
    float*          w2q  = (float*)(wsb + 6619136);             // 18,432 B
    float*          b1f  = (float*)(wsb + 6637568);             // 512 B
    float*          b2t  = (float*)(wsb + 6638080);             // 512 B

    const int fold_tasks = C*J + J + 9*D*D*P + J + P*C*8;       // 103,168
    fold_params<<<(fold_tasks + 255)/256, 256, 0, stream>>>(
        W1, B1, W2, B2, W3, B3, G1, Be1, M1, V1, G2, Be2, M2, V2,
        G3, Be3, M3, V3, W1bf, b1f, w2q, b2t, WB);

    fused12<<<8*14*7, 256, 0, stream>>>(x, W1bf, b1f, w2q, b2t, h2);
    stage3<<<(NPOS/64)*4, 256, 0, stream>>>(h2, WB, x, (float*)d_out);
}